// Round 1
// baseline (244.718 us; speedup 1.0000x reference)
//
#include <hip/hip_runtime.h>
#include <cstdint>

// BinarizedLeNet5 / CIFAR10, B=2048.
// Pipeline:
//  k2a/b/c : bitpack sign(weights) for conv2 / fc1 / fc2        (tiny)
//  k1      : conv1(fp32, +-1 w) + maxpool + bn1 sign -> 1 word per (b,y,x) [B,16,16]
//  k3      : conv2 via XOR+popc + maxpool + bn2 sign -> [B,128 words] (NCHW flatten order)
//  k4      : fc1 via XOR+popc + bn3 sign -> [B,16 words]
//  k5      : fc2 via XOR+popc + bn4 + clip -> [B,256] fp32
//  k6      : fc3 + log_softmax -> [B,10] fp32
// Binary-layer dots are exact integers == the fp32 reference sums (all < 2^24).
// BN sign tests replicate reference op order: fl(fl(h*inv)+add) > 0 with
// inv = fl(g / sqrt(v+eps)), add = fl(b - fl(m*inv)); no fma contraction.

#define BSZ 2048

// ---------------- weight packing ----------------
__global__ __launch_bounds__(256) void k2a_pack_conv2w(const float* __restrict__ w,
                                                       uint32_t* __restrict__ wp) {
    int i = blockIdx.x * 256 + threadIdx.x;          // [64 o][9 tap]
    if (i >= 64 * 9) return;
    int o = i / 9, tap = i - o * 9;
    uint32_t word = 0;
    for (int c = 0; c < 32; c++)
        if (w[(o * 32 + c) * 9 + tap] > 0.f) word |= (1u << c);
    wp[i] = word;
}

__global__ __launch_bounds__(256) void k2b_pack_fc1w(const float* __restrict__ w,
                                                     uint32_t* __restrict__ wp) {
    int i = blockIdx.x * 256 + threadIdx.x;          // 65536 = [128 k][512 o]
    int k = i >> 9, o = i & 511;
    const float* r = w + (size_t)o * 4096 + k * 32;
    uint32_t word = 0;
#pragma unroll
    for (int j = 0; j < 32; j++)
        if (r[j] > 0.f) word |= (1u << j);
    wp[k * 512 + o] = word;                          // transposed: coalesced in k4
}

__global__ __launch_bounds__(256) void k2c_pack_fc2w(const float* __restrict__ w,
                                                     uint32_t* __restrict__ wp) {
    int i = blockIdx.x * 256 + threadIdx.x;          // 4096 = [16 k][256 o]
    int k = i >> 8, o = i & 255;
    const float* r = w + (size_t)o * 512 + k * 32;
    uint32_t word = 0;
#pragma unroll
    for (int j = 0; j < 32; j++)
        if (r[j] > 0.f) word |= (1u << j);
    wp[k * 256 + o] = word;
}

// ---------------- k1: conv1 + pool + bn1 + sign-pack ----------------
// one block per sample; thread t = pooled pixel (py,px) in 16x16; computes all
// 32 output channels -> one uint32 word.
__global__ __launch_bounds__(256) void k1_conv1_pool_bn_pack(
    const float* __restrict__ x, const float* __restrict__ w,
    const float* __restrict__ cb, const float* __restrict__ g,
    const float* __restrict__ bb, const float* __restrict__ m,
    const float* __restrict__ v, uint32_t* __restrict__ out) {
    __shared__ float ws[32][28];                     // +-1 weights, padded row
    __shared__ float s_inv[32], s_add[32], s_cb[32];
    int t = threadIdx.x;
    for (int i = t; i < 32 * 27; i += 256) {
        int o = i / 27, r = i - o * 27;
        float wv = w[i];
        ws[o][r] = (wv > 0.f) ? 1.f : ((wv < 0.f) ? -1.f : 0.f);
    }
    if (t < 32) {
        float inv = __fdiv_rn(g[t], __fsqrt_rn(v[t] + 1e-5f));
        s_inv[t] = inv;
        s_add[t] = __fsub_rn(bb[t], __fmul_rn(m[t], inv));
        s_cb[t] = cb[t];
    }
    __syncthreads();
    int b = blockIdx.x;
    int py = t >> 4, px = t & 15;
    int y0 = 2 * py - 1, x0 = 2 * px - 1;
    float in[3][16];
#pragma unroll
    for (int c = 0; c < 3; c++) {
        const float* xc = x + ((size_t)b * 3 + c) * 1024;
#pragma unroll
        for (int i = 0; i < 4; i++) {
            int yy = y0 + i;
            bool ry = (unsigned)yy < 32u;
#pragma unroll
            for (int j = 0; j < 4; j++) {
                int xx = x0 + j;
                in[c][i * 4 + j] = (ry && (unsigned)xx < 32u) ? xc[yy * 32 + xx] : 0.f;
            }
        }
    }
    uint32_t word = 0;
    for (int o = 0; o < 32; o++) {
        float a00 = 0.f, a01 = 0.f, a10 = 0.f, a11 = 0.f;
#pragma unroll
        for (int c = 0; c < 3; c++)
#pragma unroll
            for (int ky = 0; ky < 3; ky++)
#pragma unroll
                for (int kx = 0; kx < 3; kx++) {
                    float wv = ws[o][c * 9 + ky * 3 + kx];
                    a00 = fmaf(in[c][ky * 4 + kx], wv, a00);
                    a01 = fmaf(in[c][ky * 4 + kx + 1], wv, a01);
                    a10 = fmaf(in[c][(ky + 1) * 4 + kx], wv, a10);
                    a11 = fmaf(in[c][(ky + 1) * 4 + kx + 1], wv, a11);
                }
        float mx = fmaxf(fmaxf(a00, a01), fmaxf(a10, a11));
        float h = __fadd_rn(mx, s_cb[o]);            // bias commutes with max
        float val = __fadd_rn(__fmul_rn(h, s_inv[o]), s_add[o]);
        if (val > 0.f) word |= (1u << o);
    }
    out[(size_t)b * 256 + t] = word;
}

// ---------------- k3: conv2 (xnor-popc) + pool + bn2 + sign-pack ----------------
// block = (b, group of 4 output channels); wave = one o; lane = pooled pixel s in 8x8.
// ballot over 64 lanes -> features [o*64, o*64+64) -> words 2o, 2o+1 of [B,128].
__global__ __launch_bounds__(256) void k3_conv2_pool_bn_pack(
    const uint32_t* __restrict__ in, const uint32_t* __restrict__ wp,
    const float* __restrict__ cb, const float* __restrict__ g,
    const float* __restrict__ bb, const float* __restrict__ m,
    const float* __restrict__ v, uint32_t* __restrict__ out) {
    int b = blockIdx.x >> 4;
    int og = blockIdx.x & 15;
    int t = threadIdx.x;
    __shared__ uint32_t li[256];
    li[t] = in[(size_t)b * 256 + t];
    __syncthreads();
    int wv_id = t >> 6, l = t & 63;
    int o = og * 4 + wv_id;
    uint32_t ww[9];
#pragma unroll
    for (int k = 0; k < 9; k++) ww[k] = wp[o * 9 + k];
    float inv = __fdiv_rn(g[o], __fsqrt_rn(v[o] + 1e-5f));
    float add = __fsub_rn(bb[o], __fmul_rn(m[o], inv));
    float cbo = cb[o];
    int py = l >> 3, px = l & 7;
    int y0 = 2 * py - 1, x0 = 2 * px - 1;
    uint32_t val[16];
    bool ok[16];
#pragma unroll
    for (int i = 0; i < 4; i++) {
        int yy = y0 + i;
        bool ry = (unsigned)yy < 16u;
#pragma unroll
        for (int j = 0; j < 4; j++) {
            int xx = x0 + j;
            bool o2 = ry && ((unsigned)xx < 16u);
            ok[i * 4 + j] = o2;
            val[i * 4 + j] = o2 ? li[yy * 16 + xx] : 0u;
        }
    }
    // pad taps contribute 0 (input is zero-padded real 0, not +-1) -> skip them.
    int s00 = 0, s01 = 0, s10 = 0, s11 = 0;
#pragma unroll
    for (int ky = 0; ky < 3; ky++)
#pragma unroll
        for (int kx = 0; kx < 3; kx++) {
            uint32_t wk = ww[ky * 3 + kx];
            int i00 = ky * 4 + kx;
            int i01 = ky * 4 + kx + 1;
            int i10 = (ky + 1) * 4 + kx;
            int i11 = (ky + 1) * 4 + kx + 1;
            s00 += ok[i00] ? (32 - 2 * __popc(val[i00] ^ wk)) : 0;
            s01 += ok[i01] ? (32 - 2 * __popc(val[i01] ^ wk)) : 0;
            s10 += ok[i10] ? (32 - 2 * __popc(val[i10] ^ wk)) : 0;
            s11 += ok[i11] ? (32 - 2 * __popc(val[i11] ^ wk)) : 0;
        }
    int mi = max(max(s00, s01), max(s10, s11));
    float h = __fadd_rn((float)mi, cbo);
    float bv = __fadd_rn(__fmul_rn(h, inv), add);
    unsigned long long mk = __ballot(bv > 0.f);
    if (l == 0) {
        out[(size_t)b * 128 + 2 * o] = (uint32_t)mk;
        out[(size_t)b * 128 + 2 * o + 1] = (uint32_t)(mk >> 32);
    }
}

// ---------------- k4: fc1 (xnor-popc) + bn3 + sign-pack ----------------
// block = (4 samples, half of the 512 outputs); lane l -> o = base+l; 4 samples
// per thread amortize the weight stream (512->134 MB of L2 traffic).
__global__ __launch_bounds__(256) void k4_fc1(
    const uint32_t* __restrict__ in, const uint32_t* __restrict__ wp,
    const float* __restrict__ fb, const float* __restrict__ g,
    const float* __restrict__ bb, const float* __restrict__ m,
    const float* __restrict__ v, uint32_t* __restrict__ out) {
    int t = threadIdx.x;
    int half = blockIdx.x & 1;
    int bg = blockIdx.x >> 1;
    int b0 = bg * 4;
    __shared__ uint32_t li[4 * 128];
    for (int i = t; i < 512; i += 256) li[i] = in[(size_t)b0 * 128 + i];
    __syncthreads();
    int wv_id = t >> 6, l = t & 63;
    int obase = half * 256 + wv_id * 64;
    int o = obase + l;
    float inv = __fdiv_rn(g[o], __fsqrt_rn(v[o] + 1e-5f));
    float add = __fsub_rn(bb[o], __fmul_rn(m[o], inv));
    float fbo = fb[o];
    int a0 = 0, a1 = 0, a2 = 0, a3 = 0;
    for (int k = 0; k < 128; k++) {
        uint32_t w = wp[k * 512 + o];                // coalesced across lanes
        a0 += __popc(w ^ li[k]);
        a1 += __popc(w ^ li[128 + k]);
        a2 += __popc(w ^ li[256 + k]);
        a3 += __popc(w ^ li[384 + k]);
    }
    int word_idx = obase >> 5;
    int accs[4] = {a0, a1, a2, a3};
#pragma unroll
    for (int nb = 0; nb < 4; nb++) {
        float h = __fadd_rn((float)(4096 - 2 * accs[nb]), fbo);
        float bv = __fadd_rn(__fmul_rn(h, inv), add);
        unsigned long long mk = __ballot(bv > 0.f);
        if (l == 0) {
            out[(size_t)(b0 + nb) * 16 + word_idx] = (uint32_t)mk;
            out[(size_t)(b0 + nb) * 16 + word_idx + 1] = (uint32_t)(mk >> 32);
        }
    }
}

// ---------------- k5: fc2 (xnor-popc) + bn4 + clip ----------------
__global__ __launch_bounds__(256) void k5_fc2(
    const uint32_t* __restrict__ in, const uint32_t* __restrict__ wp,
    const float* __restrict__ fb, const float* __restrict__ g,
    const float* __restrict__ bb, const float* __restrict__ m,
    const float* __restrict__ v, float* __restrict__ out) {
    int b = blockIdx.x, o = threadIdx.x;
    __shared__ uint32_t li[16];
    if (o < 16) li[o] = in[(size_t)b * 16 + o];
    __syncthreads();
    int acc = 0;
#pragma unroll
    for (int k = 0; k < 16; k++) acc += __popc(wp[k * 256 + o] ^ li[k]);
    float inv = __fdiv_rn(g[o], __fsqrt_rn(v[o] + 1e-5f));
    float add = __fsub_rn(bb[o], __fmul_rn(m[o], inv));
    float h = __fadd_rn((float)(512 - 2 * acc), fb[o]);
    float bv = __fadd_rn(__fmul_rn(h, inv), add);
    bv = fminf(1.f, fmaxf(-1.f, bv));                // clip feeds real fc3
    out[(size_t)b * 256 + o] = bv;
}

// ---------------- k6: fc3 + log_softmax ----------------
// one wave per sample; lane l holds h[4l..4l+3]; butterfly-reduce each of the
// 10 logits to all lanes; lanes 0..9 write.
__global__ __launch_bounds__(256) void k6_fc3_lsm(
    const float* __restrict__ h, const float* __restrict__ w,
    const float* __restrict__ fb, float* __restrict__ out) {
    int t = threadIdx.x;
    int wv_id = t >> 6, l = t & 63;
    int b = blockIdx.x * 4 + wv_id;
    const float4* hp = (const float4*)(h + (size_t)b * 256);
    float4 hv = hp[l];
    float logits[10];
#pragma unroll
    for (int j = 0; j < 10; j++) {
        const float4* wp4 = (const float4*)(w + j * 256);
        float4 w4 = wp4[l];
        float p = hv.x * w4.x + hv.y * w4.y + hv.z * w4.z + hv.w * w4.w;
#pragma unroll
        for (int off = 32; off > 0; off >>= 1) p += __shfl_xor(p, off, 64);
        logits[j] = p + fb[j];
    }
    float mx = logits[0];
#pragma unroll
    for (int j = 1; j < 10; j++) mx = fmaxf(mx, logits[j]);
    float sum = 0.f;
#pragma unroll
    for (int j = 0; j < 10; j++) sum += expf(logits[j] - mx);
    float ls = mx + logf(sum);
    if (l < 10) out[(size_t)b * 10 + l] = logits[l] - ls;
}

extern "C" void kernel_launch(void* const* d_in, const int* in_sizes, int n_in,
                              void* d_out, int out_size, void* d_ws, size_t ws_size,
                              hipStream_t stream) {
    (void)in_sizes; (void)n_in; (void)out_size; (void)ws_size;
    const float* x   = (const float*)d_in[0];
    const float* c1w = (const float*)d_in[1];
    const float* c1b = (const float*)d_in[2];
    const float* b1g = (const float*)d_in[3];
    const float* b1b = (const float*)d_in[4];
    const float* b1m = (const float*)d_in[5];
    const float* b1v = (const float*)d_in[6];
    const float* c2w = (const float*)d_in[7];
    const float* c2b = (const float*)d_in[8];
    const float* b2g = (const float*)d_in[9];
    const float* b2b = (const float*)d_in[10];
    const float* b2m = (const float*)d_in[11];
    const float* b2v = (const float*)d_in[12];
    const float* f1w = (const float*)d_in[13];
    const float* f1b = (const float*)d_in[14];
    const float* b3g = (const float*)d_in[15];
    const float* b3b = (const float*)d_in[16];
    const float* b3m = (const float*)d_in[17];
    const float* b3v = (const float*)d_in[18];
    const float* f2w = (const float*)d_in[19];
    const float* f2b = (const float*)d_in[20];
    const float* b4g = (const float*)d_in[21];
    const float* b4b = (const float*)d_in[22];
    const float* b4m = (const float*)d_in[23];
    const float* b4v = (const float*)d_in[24];
    const float* f3w = (const float*)d_in[25];
    const float* f3b = (const float*)d_in[26];
    float* out = (float*)d_out;

    uint8_t* ws = (uint8_t*)d_ws;
    uint32_t* ws1  = (uint32_t*)(ws + 0);        // [B,256]  conv2 input bits, 2 MB
    uint32_t* ws2  = (uint32_t*)(ws + 2097152);  // [B,128]  fc1 input bits,   1 MB
    uint32_t* ws3  = (uint32_t*)(ws + 3145728);  // [B,16]   fc2 input bits,   128 KB
    float*    ws4  = (float*)   (ws + 3276800);  // [B,256]  fc3 input fp32,   2 MB
    uint32_t* wpc2 = (uint32_t*)(ws + 5373952);  // [64,9]   packed conv2_w
    uint32_t* wpf1 = (uint32_t*)(ws + 5376256);  // [128,512] packed fc1_w^T
    uint32_t* wpf2 = (uint32_t*)(ws + 5638400);  // [16,256]  packed fc2_w^T

    k2a_pack_conv2w<<<3, 256, 0, stream>>>(c2w, wpc2);
    k2b_pack_fc1w<<<256, 256, 0, stream>>>(f1w, wpf1);
    k2c_pack_fc2w<<<16, 256, 0, stream>>>(f2w, wpf2);
    k1_conv1_pool_bn_pack<<<BSZ, 256, 0, stream>>>(x, c1w, c1b, b1g, b1b, b1m, b1v, ws1);
    k3_conv2_pool_bn_pack<<<BSZ * 16, 256, 0, stream>>>(ws1, wpc2, c2b, b2g, b2b, b2m, b2v, ws2);
    k4_fc1<<<1024, 256, 0, stream>>>(ws2, wpf1, f1b, b3g, b3b, b3m, b3v, ws3);
    k5_fc2<<<BSZ, 256, 0, stream>>>(ws3, wpf2, f2b, b4g, b4b, b4m, b4v, ws4);
    k6_fc3_lsm<<<512, 256, 0, stream>>>(ws4, f3w, f3b, out);
}

// Round 2
// 218.909 us; speedup vs baseline: 1.1179x; 1.1179x over previous
//
#include <hip/hip_runtime.h>
#include <cstdint>

// BinarizedLeNet5 / CIFAR10, B=2048.  Round 2.
//  k0_pack : ALL weight/bn preprocessing in one kernel (grid-partitioned):
//            fc1 bits (coalesced+ballot), conv2 bits, fc2 bits, signed conv1 w,
//            packed bn params {inv, add, bias} per layer (exact op order).
//  k1      : conv1(fp32) + maxpool + bn1 sign -> [B,16,16] words.
//            weights/bn via wave-uniform global reads -> s_load; inner loop is
//            pure v_fmac_f32 with SGPR weight operand.
//  k3      : conv2 xnor-popc + pool + bn2 sign. Zero-padded LDS tile (no bounds
//            cndmask), border fixed by exact integer correction; each wave reads
//            its 16-word window ONCE and loops 16 output channels.
//  k4      : fc1 xnor-popc + bn3 sign. Sample words via s_load (uniform), weight
//            stream coalesced vector loads.
//  k56     : fc2 + bn4 + clip fused with fc3 + log_softmax through LDS.
// All binary-layer sums are exact integers; float op order identical to the
// round-1 kernel that scored absmax 0.0.

#define BSZ 2048

__device__ __forceinline__ float sgnf(float w) {
    return (w > 0.f) ? 1.f : ((w < 0.f) ? -1.f : 0.f);
}

// ---------------- k0: all packing ----------------
__global__ __launch_bounds__(256) void k0_pack(
    const float* __restrict__ c1w, const float* __restrict__ c2w,
    const float* __restrict__ f1w, const float* __restrict__ f2w,
    const float* __restrict__ c1b, const float* __restrict__ c2b,
    const float* __restrict__ f1b, const float* __restrict__ f2b,
    const float* __restrict__ b1g, const float* __restrict__ b1b,
    const float* __restrict__ b1m, const float* __restrict__ b1v,
    const float* __restrict__ b2g, const float* __restrict__ b2b,
    const float* __restrict__ b2m, const float* __restrict__ b2v,
    const float* __restrict__ b3g, const float* __restrict__ b3b,
    const float* __restrict__ b3m, const float* __restrict__ b3v,
    const float* __restrict__ b4g, const float* __restrict__ b4b,
    const float* __restrict__ b4m, const float* __restrict__ b4v,
    float* __restrict__ sw1, uint32_t* __restrict__ wp2,
    uint32_t* __restrict__ wpf1, uint32_t* __restrict__ wpf2,
    float* __restrict__ bnp1, float* __restrict__ bnp2,
    float* __restrict__ bnp3, float* __restrict__ bnp4) {
    int bid = blockIdx.x, t = threadIdx.x;
    if (bid < 1024) {
        // fc1 pack: wave W covers 512 consecutive elements of row o.
        int W = bid * 4 + (t >> 6), l = t & 63;
        int o = W >> 3, chunk = W & 7;
        const float* row = f1w + (size_t)o * 4096 + chunk * 512;
        int kwb = chunk * 16;
#pragma unroll
        for (int j = 0; j < 8; j++) {
            float vj = row[j * 64 + l];
            unsigned long long mk = __ballot(vj > 0.f);
            if (l == 0) {
                wpf1[(size_t)(kwb + 2 * j) * 512 + o] = (uint32_t)mk;
                wpf1[(size_t)(kwb + 2 * j + 1) * 512 + o] = (uint32_t)(mk >> 32);
            }
        }
    } else if (bid == 1024) {
        // conv2 pack: wp2[o*16+k], k<9; plus bn2 params.
        for (int i = t; i < 1024; i += 256) {
            int o = i >> 4, k = i & 15;
            uint32_t word = 0;
            if (k < 9)
                for (int c = 0; c < 32; c++)
                    if (c2w[(o * 32 + c) * 9 + k] > 0.f) word |= (1u << c);
            wp2[i] = word;
        }
        if (t < 64) {
            float inv = __fdiv_rn(b2g[t], __fsqrt_rn(b2v[t] + 1e-5f));
            float add = __fsub_rn(b2b[t], __fmul_rn(b2m[t], inv));
            bnp2[t * 4] = inv; bnp2[t * 4 + 1] = add;
            bnp2[t * 4 + 2] = c2b[t]; bnp2[t * 4 + 3] = 0.f;
        }
    } else if (bid == 1025) {
        // conv1 signed weights (stride-32 rows) + bn1 params.
        for (int i = t; i < 1024; i += 256) {
            int o = i >> 5, r = i & 31;
            sw1[i] = (r < 27) ? sgnf(c1w[o * 27 + r]) : 0.f;
        }
        if (t < 32) {
            float inv = __fdiv_rn(b1g[t], __fsqrt_rn(b1v[t] + 1e-5f));
            float add = __fsub_rn(b1b[t], __fmul_rn(b1m[t], inv));
            bnp1[t * 4] = inv; bnp1[t * 4 + 1] = add;
            bnp1[t * 4 + 2] = c1b[t]; bnp1[t * 4 + 3] = 0.f;
        }
    } else if (bid < 1042) {
        // fc2 pack: wpf2[k*256+o]
        int i = (bid - 1026) * 256 + t;       // 4096 = [16 k][256 o]
        int k = i >> 8, o = i & 255;
        const float* r = f2w + (size_t)o * 512 + k * 32;
        uint32_t word = 0;
#pragma unroll
        for (int j = 0; j < 32; j++)
            if (r[j] > 0.f) word |= (1u << j);
        wpf2[k * 256 + o] = word;
    } else {
        // bn3 + bn4 params (with fc biases folded in slot .z)
        for (int i = t; i < 512; i += 256) {
            float inv = __fdiv_rn(b3g[i], __fsqrt_rn(b3v[i] + 1e-5f));
            float add = __fsub_rn(b3b[i], __fmul_rn(b3m[i], inv));
            bnp3[i * 4] = inv; bnp3[i * 4 + 1] = add;
            bnp3[i * 4 + 2] = f1b[i]; bnp3[i * 4 + 3] = 0.f;
        }
        if (t < 256) {
            float inv = __fdiv_rn(b4g[t], __fsqrt_rn(b4v[t] + 1e-5f));
            float add = __fsub_rn(b4b[t], __fmul_rn(b4m[t], inv));
            bnp4[t * 4] = inv; bnp4[t * 4 + 1] = add;
            bnp4[t * 4 + 2] = f2b[t]; bnp4[t * 4 + 3] = 0.f;
        }
    }
}

// ---------------- k1: conv1 + pool + bn1 + sign-pack ----------------
__global__ __launch_bounds__(256) void k1_conv1(
    const float* __restrict__ x, const float* __restrict__ sw,
    const float* __restrict__ bnp, uint32_t* __restrict__ out) {
    int b = blockIdx.x, t = threadIdx.x;
    int py = t >> 4, px = t & 15;
    int y0 = 2 * py - 1, x0 = 2 * px - 1;
    float in[48];
#pragma unroll
    for (int c = 0; c < 3; c++) {
        const float* xc = x + ((size_t)b * 3 + c) * 1024;
#pragma unroll
        for (int i = 0; i < 4; i++) {
            int yy = y0 + i;
            bool ry = (unsigned)yy < 32u;
#pragma unroll
            for (int j = 0; j < 4; j++) {
                int xx = x0 + j;
                in[c * 16 + i * 4 + j] =
                    (ry && (unsigned)xx < 32u) ? xc[yy * 32 + xx] : 0.f;
            }
        }
    }
    uint32_t word = 0;
#pragma unroll 2
    for (int o = 0; o < 32; o++) {
        const float* wo = sw + o * 32;           // uniform -> s_load
        float a00 = 0.f, a01 = 0.f, a10 = 0.f, a11 = 0.f;
#pragma unroll
        for (int c = 0; c < 3; c++)
#pragma unroll
            for (int ky = 0; ky < 3; ky++)
#pragma unroll
                for (int kx = 0; kx < 3; kx++) {
                    float wv = wo[c * 9 + ky * 3 + kx];
                    a00 = fmaf(in[c * 16 + ky * 4 + kx], wv, a00);
                    a01 = fmaf(in[c * 16 + ky * 4 + kx + 1], wv, a01);
                    a10 = fmaf(in[c * 16 + (ky + 1) * 4 + kx], wv, a10);
                    a11 = fmaf(in[c * 16 + (ky + 1) * 4 + kx + 1], wv, a11);
                }
        float4 p = ((const float4*)bnp)[o];      // uniform -> s_load
        float mx = fmaxf(fmaxf(a00, a01), fmaxf(a10, a11));
        float h = __fadd_rn(mx, p.z);
        float val = __fadd_rn(__fmul_rn(h, p.x), p.y);
        word |= (val > 0.f) ? (1u << o) : 0u;
    }
    out[(size_t)b * 256 + t] = word;
}

// ---------------- k3: conv2 xnor-popc + pool + bn2 + sign-pack ----------------
// block = sample; zero-padded 18x19 tile; wave wv does o in [wv*16, wv*16+16),
// reusing its 16-word window across all 16 channels.
__global__ __launch_bounds__(256) void k3_conv2(
    const uint32_t* __restrict__ in, const uint32_t* __restrict__ wp,
    const float* __restrict__ bnp, uint32_t* __restrict__ out) {
    int b = blockIdx.x, t = threadIdx.x;
    const int P = 19;
    __shared__ uint32_t tile[18 * 19];
    for (int i = t; i < 18 * 19; i += 256) tile[i] = 0;
    __syncthreads();
    {
        int y = t >> 4, xx = t & 15;
        tile[(y + 1) * P + xx + 1] = in[(size_t)b * 256 + t];
    }
    __syncthreads();
    int wv = t >> 6, l = t & 63;
    int py = l >> 3, px = l & 7;
    uint32_t val[16];
#pragma unroll
    for (int i = 0; i < 4; i++)
#pragma unroll
        for (int j = 0; j < 4; j++)
            val[i * 4 + j] = tile[(2 * py + i) * P + 2 * px + j];
    bool top = (py == 0), bot = (py == 7), lef = (px == 0), rig = (px == 7);
    bool ctl = top && lef, ctr = top && rig, cbl = bot && lef, cbr = bot && rig;
#pragma unroll 2
    for (int oi = 0; oi < 16; oi++) {
        int o = wv * 16 + oi;
        const uint32_t* wo = wp + o * 16;        // uniform -> s_load
        uint32_t w0 = wo[0], w1 = wo[1], w2 = wo[2], w3 = wo[3], w4 = wo[4],
                 w5 = wo[5], w6 = wo[6], w7 = wo[7], w8 = wo[8];
        int t0 = 32 - 2 * __popc(w0), t1 = 32 - 2 * __popc(w1),
            t2 = 32 - 2 * __popc(w2), t3 = 32 - 2 * __popc(w3),
            t5 = 32 - 2 * __popc(w5), t6 = 32 - 2 * __popc(w6),
            t7 = 32 - 2 * __popc(w7), t8 = 32 - 2 * __popc(w8);
        int t4v = 32 - 2 * __popc(w4);
        int R0 = t0 + t1 + t2, R2 = t6 + t7 + t8;
        int C0 = t0 + t3 + t6, C2 = t2 + t5 + t8;
        (void)t4v;
        int P00 = __popc(val[0] ^ w0) + __popc(val[1] ^ w1) + __popc(val[2] ^ w2) +
                  __popc(val[4] ^ w3) + __popc(val[5] ^ w4) + __popc(val[6] ^ w5) +
                  __popc(val[8] ^ w6) + __popc(val[9] ^ w7) + __popc(val[10] ^ w8);
        int P01 = __popc(val[1] ^ w0) + __popc(val[2] ^ w1) + __popc(val[3] ^ w2) +
                  __popc(val[5] ^ w3) + __popc(val[6] ^ w4) + __popc(val[7] ^ w5) +
                  __popc(val[9] ^ w6) + __popc(val[10] ^ w7) + __popc(val[11] ^ w8);
        int P10 = __popc(val[4] ^ w0) + __popc(val[5] ^ w1) + __popc(val[6] ^ w2) +
                  __popc(val[8] ^ w3) + __popc(val[9] ^ w4) + __popc(val[10] ^ w5) +
                  __popc(val[12] ^ w6) + __popc(val[13] ^ w7) + __popc(val[14] ^ w8);
        int P11 = __popc(val[5] ^ w0) + __popc(val[6] ^ w1) + __popc(val[7] ^ w2) +
                  __popc(val[9] ^ w3) + __popc(val[10] ^ w4) + __popc(val[11] ^ w5) +
                  __popc(val[13] ^ w6) + __popc(val[14] ^ w7) + __popc(val[15] ^ w8);
        // border corrections (padded zeros contributed t_k per pad tap)
        int s00 = 288 - 2 * P00 - ((top ? R0 : 0) + (lef ? C0 : 0) - (ctl ? t0 : 0));
        int s01 = 288 - 2 * P01 - ((top ? R0 : 0) + (rig ? C2 : 0) - (ctr ? t2 : 0));
        int s10 = 288 - 2 * P10 - ((bot ? R2 : 0) + (lef ? C0 : 0) - (cbl ? t6 : 0));
        int s11 = 288 - 2 * P11 - ((bot ? R2 : 0) + (rig ? C2 : 0) - (cbr ? t8 : 0));
        int mi = max(max(s00, s01), max(s10, s11));
        float4 p = ((const float4*)bnp)[o];      // uniform -> s_load
        float h = __fadd_rn((float)mi, p.z);
        float bv = __fadd_rn(__fmul_rn(h, p.x), p.y);
        unsigned long long mk = __ballot(bv > 0.f);
        if (l == 0) {
            out[(size_t)b * 128 + 2 * o] = (uint32_t)mk;
            out[(size_t)b * 128 + 2 * o + 1] = (uint32_t)(mk >> 32);
        }
    }
}

// ---------------- k4: fc1 xnor-popc + bn3 + sign-pack ----------------
__global__ __launch_bounds__(256) void k4_fc1(
    const uint32_t* __restrict__ in, const uint32_t* __restrict__ wp,
    const float* __restrict__ bnp, uint32_t* __restrict__ out) {
    int t = threadIdx.x;
    int half = blockIdx.x & 1, bg = blockIdx.x >> 1;
    int b0 = bg * 4;
    int wv = t >> 6, l = t & 63;
    int obase = half * 256 + wv * 64;
    int o = obase + l;
    float4 p = ((const float4*)bnp)[o];          // per-lane, coalesced
    const uint32_t* s0 = in + (size_t)b0 * 128;  // uniform -> s_load
    int a0 = 0, a1 = 0, a2 = 0, a3 = 0;
#pragma unroll 8
    for (int k = 0; k < 128; k++) {
        uint32_t w = wp[k * 512 + o];            // coalesced vector load
        a0 += __popc(w ^ s0[k]);
        a1 += __popc(w ^ s0[128 + k]);
        a2 += __popc(w ^ s0[256 + k]);
        a3 += __popc(w ^ s0[384 + k]);
    }
    int word_idx = obase >> 5;
    int accs[4] = {a0, a1, a2, a3};
#pragma unroll
    for (int nb = 0; nb < 4; nb++) {
        float h = __fadd_rn((float)(4096 - 2 * accs[nb]), p.z);
        float bv = __fadd_rn(__fmul_rn(h, p.x), p.y);
        unsigned long long mk = __ballot(bv > 0.f);
        if (l == 0) {
            out[(size_t)(b0 + nb) * 16 + word_idx] = (uint32_t)mk;
            out[(size_t)(b0 + nb) * 16 + word_idx + 1] = (uint32_t)(mk >> 32);
        }
    }
}

// ---------------- k56: fc2 + bn4 + clip + fc3 + log_softmax ----------------
__global__ __launch_bounds__(256) void k56_fc23(
    const uint32_t* __restrict__ in, const uint32_t* __restrict__ wp,
    const float* __restrict__ bnp, const float* __restrict__ f3w,
    const float* __restrict__ f3b, float* __restrict__ out) {
    int b = blockIdx.x, t = threadIdx.x;
    __shared__ uint32_t li[16];
    __shared__ float hbuf[256];
    if (t < 16) li[t] = in[(size_t)b * 16 + t];
    __syncthreads();
    int acc = 0;
#pragma unroll
    for (int k = 0; k < 16; k++) acc += __popc(wp[k * 256 + t] ^ li[k]);
    float4 p = ((const float4*)bnp)[t];
    float h = __fadd_rn((float)(512 - 2 * acc), p.z);
    float bv = __fadd_rn(__fmul_rn(h, p.x), p.y);
    bv = fminf(1.f, fmaxf(-1.f, bv));
    hbuf[t] = bv;
    __syncthreads();
    if (t < 64) {
        float4 hv = ((const float4*)hbuf)[t];
        float logits[10];
#pragma unroll
        for (int j = 0; j < 10; j++) {
            const float4* wp4 = (const float4*)(f3w + j * 256);
            float4 w4 = wp4[t];
            float pp = hv.x * w4.x + hv.y * w4.y + hv.z * w4.z + hv.w * w4.w;
#pragma unroll
            for (int off = 32; off > 0; off >>= 1) pp += __shfl_xor(pp, off, 64);
            logits[j] = pp + f3b[j];
        }
        float mx = logits[0];
#pragma unroll
        for (int j = 1; j < 10; j++) mx = fmaxf(mx, logits[j]);
        float sum = 0.f;
#pragma unroll
        for (int j = 0; j < 10; j++) sum += expf(logits[j] - mx);
        float ls = mx + logf(sum);
        if (t < 10) out[(size_t)b * 10 + t] = logits[t] - ls;
    }
}

extern "C" void kernel_launch(void* const* d_in, const int* in_sizes, int n_in,
                              void* d_out, int out_size, void* d_ws, size_t ws_size,
                              hipStream_t stream) {
    (void)in_sizes; (void)n_in; (void)out_size; (void)ws_size;
    const float* x   = (const float*)d_in[0];
    const float* c1w = (const float*)d_in[1];
    const float* c1b = (const float*)d_in[2];
    const float* b1g = (const float*)d_in[3];
    const float* b1b = (const float*)d_in[4];
    const float* b1m = (const float*)d_in[5];
    const float* b1v = (const float*)d_in[6];
    const float* c2w = (const float*)d_in[7];
    const float* c2b = (const float*)d_in[8];
    const float* b2g = (const float*)d_in[9];
    const float* b2b = (const float*)d_in[10];
    const float* b2m = (const float*)d_in[11];
    const float* b2v = (const float*)d_in[12];
    const float* f1w = (const float*)d_in[13];
    const float* f1b = (const float*)d_in[14];
    const float* b3g = (const float*)d_in[15];
    const float* b3b = (const float*)d_in[16];
    const float* b3m = (const float*)d_in[17];
    const float* b3v = (const float*)d_in[18];
    const float* f2w = (const float*)d_in[19];
    const float* f2b = (const float*)d_in[20];
    const float* b4g = (const float*)d_in[21];
    const float* b4b = (const float*)d_in[22];
    const float* b4m = (const float*)d_in[23];
    const float* b4v = (const float*)d_in[24];
    const float* f3w = (const float*)d_in[25];
    const float* f3b = (const float*)d_in[26];
    float* out = (float*)d_out;

    uint8_t* ws = (uint8_t*)d_ws;
    uint32_t* ws1  = (uint32_t*)(ws + 0);         // [B,256] conv2 in bits  2 MB
    uint32_t* ws2  = (uint32_t*)(ws + 2097152);   // [B,128] fc1 in bits    1 MB
    uint32_t* ws3  = (uint32_t*)(ws + 3145728);   // [B,16]  fc2 in bits  128 KB
    float*    sw1  = (float*)   (ws + 3276800);   // [32,32] signed conv1 w
    uint32_t* wp2  = (uint32_t*)(ws + 3280896);   // [64,16] conv2 bits
    uint32_t* wpf1 = (uint32_t*)(ws + 3284992);   // [128,512] fc1 bits^T
    uint32_t* wpf2 = (uint32_t*)(ws + 3547136);   // [16,256]  fc2 bits^T
    float*    bnp1 = (float*)   (ws + 3563520);   // [32]  {inv,add,bias,0}
    float*    bnp2 = (float*)   (ws + 3564032);   // [64]
    float*    bnp3 = (float*)   (ws + 3565056);   // [512]
    float*    bnp4 = (float*)   (ws + 3573248);   // [256]

    k0_pack<<<1043, 256, 0, stream>>>(c1w, c2w, f1w, f2w, c1b, c2b, f1b, f2b,
                                      b1g, b1b, b1m, b1v, b2g, b2b, b2m, b2v,
                                      b3g, b3b, b3m, b3v, b4g, b4b, b4m, b4v,
                                      sw1, wp2, wpf1, wpf2, bnp1, bnp2, bnp3, bnp4);
    k1_conv1<<<BSZ, 256, 0, stream>>>(x, sw1, bnp1, ws1);
    k3_conv2<<<BSZ, 256, 0, stream>>>(ws1, wp2, bnp2, ws2);
    k4_fc1<<<1024, 256, 0, stream>>>(ws2, wpf1, bnp3, ws3);
    k56_fc23<<<BSZ, 256, 0, stream>>>(ws3, wpf2, bnp4, f3w, f3b, out);
}